// Round 7
// baseline (164.987 us; speedup 1.0000x reference)
//
#include <hip/hip_runtime.h>

typedef unsigned char u8;
typedef float f32x4 __attribute__((ext_vector_type(4)));
typedef float f32x16 __attribute__((ext_vector_type(16)));

#define LL 4096
#define PSTR 72               // P row stride (bytes): 2 lanes/bank on P writes (verified R6-class)
#define SCALE 16.0f           // x pre-scale before fp8
#define GSCALE (1.0f/256.0f)  // undo SCALE^2 on the gram
#define FREQC (-0.03597789207803197f)   // -ln(10000)/256

__device__ __forceinline__ long LCAST(uint2 v) { return __builtin_bit_cast(long, v); }

typedef __attribute__((address_space(3))) u8 lds_u8;
typedef __attribute__((address_space(1))) u8 glb_u8;
__device__ __forceinline__ void dma16(const u8* g, u8* l) {
  __builtin_amdgcn_global_load_lds((const glb_u8*)g, (lds_u8*)l, 16, 0, 0);
}

// ---------------- prep1 (verbatim R5/R6 — validated): fp8 convert, swizzled layouts ----------------
// xbf: row r (256 B): 8-B chunk c stored at ((c ^ (r&31))*8).
// xT : d-row (4096 B) split into 32 j-segments of 128 B; chunk c in segment at ((c ^ (d&15))*8).
__global__ __launch_bounds__(256) void prep1(const float* __restrict__ x, u8* __restrict__ xbf,
                                             u8* __restrict__ xT, float* __restrict__ sq) {
  __shared__ u8 T[16 * 264];
  const int blk = blockIdx.x;
  const int b = blk >> 8, r0 = (blk & 255) << 4;
  const int tid = threadIdx.x;
  const long rowbase = (long)(b << 12) + r0;
  const float4* x4 = (const float4*)x + rowbase * 64;
  unsigned* xb4 = (unsigned*)xbf + rowbase * 64;
  #pragma unroll
  for (int i = 0; i < 4; ++i) {
    int idx = i * 256 + tid;
    float4 v = x4[idx];
    float s = v.x * v.x + v.y * v.y + v.z * v.z + v.w * v.w;
    #pragma unroll
    for (int o = 32; o; o >>= 1) s += __shfl_xor(s, o);
    int row = idx >> 6, dw = idx & 63;
    if ((tid & 63) == 0) sq[rowbase + row] = s;
    int pk = __builtin_amdgcn_cvt_pk_fp8_f32(v.x * SCALE, v.y * SCALE, 0, false);
    pk = __builtin_amdgcn_cvt_pk_fp8_f32(v.z * SCALE, v.w * SCALE, pk, true);
    int sdw = (((dw >> 1) ^ ((r0 + row) & 31)) << 1) | (dw & 1);
    xb4[row * 64 + sdw] = (unsigned)pk;
    *(unsigned*)(T + row * 264 + dw * 4) = (unsigned)pk;
  }
  __syncthreads();
  unsigned ob[4];
  #pragma unroll
  for (int jj = 0; jj < 4; ++jj) {
    unsigned b0 = T[(4 * jj + 0) * 264 + tid];
    unsigned b1 = T[(4 * jj + 1) * 264 + tid];
    unsigned b2 = T[(4 * jj + 2) * 264 + tid];
    unsigned b3 = T[(4 * jj + 3) * 264 + tid];
    ob[jj] = b0 | (b1 << 8) | (b2 << 16) | (b3 << 24);
  }
  u8* drow = xT + ((((long)(b << 8) + tid) << 12)) + ((r0 >> 7) << 7);
  const int cb = (r0 & 127) >> 3, key = tid & 15;
  *(uint2*)(drow + ((cb ^ key) << 3)) = *(uint2*)(ob);
  *(uint2*)(drow + (((cb + 1) ^ key) << 3)) = *(uint2*)(ob + 2);
}

// ---------------- main fused kernel ----------------
// 256 blocks x 512 thr (1 block/CU, 8 waves). Block = (batch, 64 Q rows).
// K-tile 64, 64 iters, ONE barrier/iter. K/V triple-buffered LDS (global_load_lds w16),
// P double-buffered. Iter: [DMA(it+1) | mm2(it-1) | mm1(it) | exp->P | barrier].
// mm1 (16x16x32 fp8, S^T): wave w -> j-strip 16*(w&3), i-strips t = 2*(w>>2)+{0,1}.
// mm2 (32x32x16 fp8): wave w -> O[64][32w..32w+31]; A = P (LDS), B = V tile (LDS).
__global__ __launch_bounds__(512, 1) void tpe_main(
    const u8* __restrict__ xbf, const u8* __restrict__ xT,
    const float* __restrict__ sqv,
    const float* __restrict__ x, float* __restrict__ out) {
  __shared__ u8 Kt[3][16384];    // K tile 64 rows x 256 B (row-swizzled, as xbf)
  __shared__ u8 Vt[3][16384];    // V tile 256 d-rows x 64 B (chunk-swizzled, key d&7)
  __shared__ u8 Ps[2][64 * PSTR];
  __shared__ float lred[8][32];
  __shared__ float linv[64];

  const int tid = threadIdx.x;
  const int w = tid >> 6;
  const int lane = tid & 63;
  const int l15 = lane & 15, l31 = lane & 31;
  const int q4 = lane >> 4;   // 0..3
  const int q2 = lane >> 5;   // 0..1
  const int wj = w & 3;       // mm1 j-strip
  const int wh = w >> 2;      // mm1 i-half (rows 32wh..32wh+31)

  // XCD pinning: batch -> XCD pair (2 MB fp8 set stays L2-hot)
  const int blk = blockIdx.x;
  const int b = (blk & 7) >> 1;
  const int qt = ((blk >> 3) << 1) | (blk & 1);
  const int q0 = qt << 6;
  const long bL = (long)b * LL;

  // Q fragments: 2 i-strips per wave (32 VGPRs)
  uint2 qf[2][8];
  float qa[2];
  #pragma unroll
  for (int t2 = 0; t2 < 2; ++t2) {
    const int row = q0 + 16 * (2 * wh + t2) + l15;
    const u8* qrow = xbf + ((bL + row) << 8);
    const int key = row & 31;
    #pragma unroll
    for (int s = 0; s < 8; ++s)
      qf[t2][s] = *(const uint2*)(qrow + (((q4 + 4 * s) ^ key) << 3));
    qa[t2] = -0.5f * sqv[bL + row];
  }

  f32x16 oacc[2];
  #pragma unroll
  for (int rb = 0; rb < 2; ++rb)
    #pragma unroll
    for (int k = 0; k < 16; ++k) oacc[rb][k] = 0.f;
  float rsacc[2] = {0.f, 0.f};

  const u8* kbat = xbf + (bL << 8);
  const long vbat = ((long)(b << 8)) << 12;
  const int d0 = tid >> 2, c16 = tid & 3;
  const u8* vsrc0 = xT + vbat + ((long)d0 << 12) + c16 * 16;
  const u8* vsrc1 = vsrc0 + ((long)128 << 12);
  const int vbit = (d0 >> 3) & 1;

  // rotating buffer pointers (invariant at iter it: ktR=it%3, ktW=(it+1)%3; vtP=(it-1)%3, vtC=it%3, vtW=(it+1)%3)
  u8 *ktR = Kt[0], *ktW = Kt[1], *ktI = Kt[2];
  u8 *vtP = Vt[2], *vtC = Vt[0], *vtW = Vt[1];
  u8 *pR = Ps[1], *pW = Ps[0];

  // prologue: DMA tile 0 -> buf 0
  dma16(kbat + tid * 16, Kt[0] + tid * 16);
  dma16(kbat + 8192 + tid * 16, Kt[0] + 8192 + tid * 16);
  {
    long voff = (long)(vbit << 6);          // g=0: sg=0, h=0
    dma16(vsrc0 + voff, Vt[0] + tid * 16);
    dma16(vsrc1 + voff, Vt[0] + 8192 + tid * 16);
  }
  __syncthreads();

  for (int it = 0; it < 64; ++it) {
    // ---- DMA tile it+1 -> write buffers (full iteration of flight time) ----
    if (it < 63) {
      const int g = it + 1;
      const u8* ks = kbat + ((long)g << 14) + tid * 16;
      dma16(ks, ktW + tid * 16);
      dma16(ks + 8192, ktW + 8192 + tid * 16);
      long voff = (long)((g >> 1) << 7) + (((g ^ vbit) & 1) << 6);
      dma16(vsrc0 + voff, vtW + tid * 16);
      dma16(vsrc1 + voff, vtW + 8192 + tid * 16);
    }
    float4 skv4 = *(const float4*)(sqv + bL + (it << 6) + 16 * wj + 4 * q4);
    // ---- mm2 on previous tile (P[it-1], V[it-1]) ----
    if (it != 0) {
      const int vkey = l31 & 7;
      const u8* vrow = vtP + ((32 * w + l31) << 6);
      #pragma unroll
      for (int s = 0; s < 4; ++s) {
        uint2 bv = *(const uint2*)(vrow + (((2 * s + q2) ^ vkey) << 3));
        long a0 = *(const long*)(pR + l31 * PSTR + 16 * s + 8 * q2);
        long a1 = *(const long*)(pR + (32 + l31) * PSTR + 16 * s + 8 * q2);
        oacc[0] = __builtin_amdgcn_mfma_f32_32x32x16_fp8_fp8(a0, LCAST(bv), oacc[0], 0, 0, 0);
        oacc[1] = __builtin_amdgcn_mfma_f32_32x32x16_fp8_fp8(a1, LCAST(bv), oacc[1], 0, 0, 0);
      }
    }
    // ---- mm1: S^T = K.Q^T on current tile ----
    {
      const int krow = 16 * wj + l15;
      const int kkey = krow & 31;
      const u8* kb2 = ktR + krow * 256;
      f32x4 s0, s1;
      s0[0] = 0.f; s0[1] = 0.f; s0[2] = 0.f; s0[3] = 0.f;
      s1[0] = 0.f; s1[1] = 0.f; s1[2] = 0.f; s1[3] = 0.f;
      #pragma unroll
      for (int s = 0; s < 8; ++s) {
        uint2 kf = *(const uint2*)(kb2 + (((q4 + 4 * s) ^ kkey) << 3));
        long av = LCAST(kf);
        s0 = __builtin_amdgcn_mfma_f32_16x16x32_fp8_fp8(av, LCAST(qf[0][s]), s0, 0, 0, 0);
        s1 = __builtin_amdgcn_mfma_f32_16x16x32_fp8_fp8(av, LCAST(qf[1][s]), s1, 0, 0, 0);
      }
      // ---- P = exp(min(0, g - 0.5||q||^2 - 0.5||k||^2)) -> LDS (fp8) ----
      #pragma unroll
      for (int t2 = 0; t2 < 2; ++t2) {
        f32x4 sa = t2 ? s1 : s0;   // lane: P[i=16*(2wh+t2)+l15][j=16wj+4q4+0..3]
        float p0 = __expf(fminf(fmaf(sa[0], GSCALE, qa[t2] + skv4.x), 0.f));
        float p1 = __expf(fminf(fmaf(sa[1], GSCALE, qa[t2] + skv4.y), 0.f));
        float p2 = __expf(fminf(fmaf(sa[2], GSCALE, qa[t2] + skv4.z), 0.f));
        float p3 = __expf(fminf(fmaf(sa[3], GSCALE, qa[t2] + skv4.w), 0.f));
        rsacc[t2] += (p0 + p1) + (p2 + p3);
        int pk = __builtin_amdgcn_cvt_pk_fp8_f32(p0, p1, 0, false);
        pk = __builtin_amdgcn_cvt_pk_fp8_f32(p2, p3, pk, true);
        *(int*)(pW + (16 * (2 * wh + t2) + l15) * PSTR + 16 * wj + 4 * q4) = pk;
      }
    }
    __syncthreads();   // the ONLY barrier: P visible, DMA(it+1) drained (full iter in flight)
    // rotate buffers
    u8* t0 = ktR; ktR = ktW; ktW = ktI; ktI = t0;
    u8* t1 = vtP; vtP = vtC; vtC = vtW; vtW = t1;
    u8* t2p = pR; pR = pW; pW = t2p;
  }
  // ---- final mm2 (tile 63) ----
  {
    const int vkey = l31 & 7;
    const u8* vrow = vtP + ((32 * w + l31) << 6);
    #pragma unroll
    for (int s = 0; s < 4; ++s) {
      uint2 bv = *(const uint2*)(vrow + (((2 * s + q2) ^ vkey) << 3));
      long a0 = *(const long*)(pR + l31 * PSTR + 16 * s + 8 * q2);
      long a1 = *(const long*)(pR + (32 + l31) * PSTR + 16 * s + 8 * q2);
      oacc[0] = __builtin_amdgcn_mfma_f32_32x32x16_fp8_fp8(a0, LCAST(bv), oacc[0], 0, 0, 0);
      oacc[1] = __builtin_amdgcn_mfma_f32_32x32x16_fp8_fp8(a1, LCAST(bv), oacc[1], 0, 0, 0);
    }
  }

  // ---- epilogue: rowsum reduce; out = O/(16*l) + x + pe(inline) ----
  #pragma unroll
  for (int t2 = 0; t2 < 2; ++t2) {
    float r = rsacc[t2];
    r += __shfl_xor(r, 16);
    r += __shfl_xor(r, 32);
    if (lane < 16) lred[w][16 * t2 + l15] = r;
  }
  __syncthreads();
  if (tid < 64) {
    const int base = (tid >> 5) << 2, idx = tid & 31;
    float s = lred[base][idx] + lred[base + 1][idx] + lred[base + 2][idx] + lred[base + 3][idx];
    linv[tid] = 0.0625f / s;   // 1/16 undoes V pre-scale
  }
  __syncthreads();
  const int col = 32 * w + l31;
  const float freq = __expf((float)(col & ~1) * FREQC);
  #pragma unroll
  for (int rb = 0; rb < 2; ++rb) {
    #pragma unroll
    for (int reg = 0; reg < 16; ++reg) {
      int row = 32 * rb + 4 * q2 + (reg & 3) + 8 * (reg >> 2);
      int l = q0 + row;
      float ang = (float)l * freq;
      float pv = (col & 1) ? __cosf(ang) : __sinf(ang);
      long off = ((bL + l) << 8) + col;
      out[off] = oacc[rb][reg] * linv[row] + x[off] + pv;
    }
  }
}

extern "C" void kernel_launch(void* const* d_in, const int* in_sizes, int n_in,
                              void* d_out, int out_size, void* d_ws, size_t ws_size,
                              hipStream_t stream) {
  const float* x = (const float*)d_in[0];
  float* out = (float*)d_out;
  char* ws = (char*)d_ws;
  u8* xbf = (u8*)ws;                       // 4,194,304 B  (fp8 x, swizzled rows)
  u8* xT = (u8*)(ws + 4194304);            // 4,194,304 B  (fp8 x^T, swizzled segments)
  float* sq = (float*)(ws + 8388608);      //    65,536 B
  prep1<<<1024, 256, 0, stream>>>(x, xbf, xT, sq);
  tpe_main<<<256, 512, 0, stream>>>(xbf, xT, sq, x, out);
}

// Round 8
// 139.678 us; speedup vs baseline: 1.1812x; 1.1812x over previous
//
#include <hip/hip_runtime.h>

typedef unsigned char u8;
typedef float f32x4 __attribute__((ext_vector_type(4)));
typedef float f32x16 __attribute__((ext_vector_type(16)));

#define LL 4096
#define PSTR 136              // P row stride (bytes): 2-lane/bank writes (free), validated R5
#define SCALE 16.0f           // x pre-scale before fp8
#define GSCALE (1.0f/256.0f)  // undo SCALE^2 on the gram
#define FREQC (-0.03597789207803197f)   // -ln(10000)/256

__device__ __forceinline__ long LCAST(uint2 v) { return __builtin_bit_cast(long, v); }

typedef __attribute__((address_space(3))) u8 lds_u8;
typedef __attribute__((address_space(1))) u8 glb_u8;
__device__ __forceinline__ void dma16(const u8* g, u8* l) {
  __builtin_amdgcn_global_load_lds((const glb_u8*)g, (lds_u8*)l, 16, 0, 0);
}

// ---------------- prep1 (verbatim R5-R7 — validated): fp8 convert, swizzled layouts ----------------
// xbf: row r (256 B): 8-B chunk c stored at ((c ^ (r&31))*8).
// xT : d-row (4096 B) split into 32 j-segments of 128 B; chunk c in segment at ((c ^ (d&15))*8).
__global__ __launch_bounds__(256) void prep1(const float* __restrict__ x, u8* __restrict__ xbf,
                                             u8* __restrict__ xT, float* __restrict__ sq) {
  __shared__ u8 T[16 * 264];
  const int blk = blockIdx.x;
  const int b = blk >> 8, r0 = (blk & 255) << 4;
  const int tid = threadIdx.x;
  const long rowbase = (long)(b << 12) + r0;
  const float4* x4 = (const float4*)x + rowbase * 64;
  unsigned* xb4 = (unsigned*)xbf + rowbase * 64;
  #pragma unroll
  for (int i = 0; i < 4; ++i) {
    int idx = i * 256 + tid;
    float4 v = x4[idx];
    float s = v.x * v.x + v.y * v.y + v.z * v.z + v.w * v.w;
    #pragma unroll
    for (int o = 32; o; o >>= 1) s += __shfl_xor(s, o);
    int row = idx >> 6, dw = idx & 63;
    if ((tid & 63) == 0) sq[rowbase + row] = s;
    int pk = __builtin_amdgcn_cvt_pk_fp8_f32(v.x * SCALE, v.y * SCALE, 0, false);
    pk = __builtin_amdgcn_cvt_pk_fp8_f32(v.z * SCALE, v.w * SCALE, pk, true);
    int sdw = (((dw >> 1) ^ ((r0 + row) & 31)) << 1) | (dw & 1);
    xb4[row * 64 + sdw] = (unsigned)pk;
    *(unsigned*)(T + row * 264 + dw * 4) = (unsigned)pk;
  }
  __syncthreads();
  unsigned ob[4];
  #pragma unroll
  for (int jj = 0; jj < 4; ++jj) {
    unsigned b0 = T[(4 * jj + 0) * 264 + tid];
    unsigned b1 = T[(4 * jj + 1) * 264 + tid];
    unsigned b2 = T[(4 * jj + 2) * 264 + tid];
    unsigned b3 = T[(4 * jj + 3) * 264 + tid];
    ob[jj] = b0 | (b1 << 8) | (b2 << 16) | (b3 << 24);
  }
  u8* drow = xT + ((((long)(b << 8) + tid) << 12)) + ((r0 >> 7) << 7);
  const int cb = (r0 & 127) >> 3, key = tid & 15;
  *(uint2*)(drow + ((cb ^ key) << 3)) = *(uint2*)(ob);
  *(uint2*)(drow + (((cb + 1) ^ key) << 3)) = *(uint2*)(ob + 2);
}

// ---------------- main fused kernel ----------------
// 256 blocks x 512 thr (1 block/CU, 8 waves). Block = (batch, 64 Q rows).
// K-tile 128, 32 iters, ONE barrier/iter. K dbuf LDS (global_load_lds w16, full-iter flight),
// P dbuf LDS, V fragments in dbuf REGISTERS (loaded pre-barrier, consumed post-barrier).
// Iter: [DMA K(it+1) | mm2(it-1): P(it-1)+vf | vf-load(it) | mm1(it): 32-MFMA run | exp->P(it) | barrier].
// mm1 (16x16x32 fp8, S^T): wave w -> j-strip 16w, all 4 Q i-strips (4 chains).
// mm2 (32x32x16 fp8): wave w -> O[64][32w..32w+31].
__global__ __launch_bounds__(512, 2) void tpe_main(
    const u8* __restrict__ xbf, const u8* __restrict__ xT,
    const float* __restrict__ sqv,
    const float* __restrict__ x, float* __restrict__ out) {
  __shared__ u8 Kt[2][32768];    // K tile 128 rows x 256 B (row-swizzled, as xbf)
  __shared__ u8 Ps[2][64 * PSTR];
  __shared__ float lred[8][64];
  __shared__ float linv[64];

  const int tid = threadIdx.x;
  const int w = tid >> 6;
  const int lane = tid & 63;
  const int l15 = lane & 15, l31 = lane & 31;
  const int q4 = lane >> 4;   // 0..3
  const int q2 = lane >> 5;   // 0..1

  // XCD pinning: batch -> XCD pair (2 MB fp8 set stays L2-hot)
  const int blk = blockIdx.x;
  const int b = (blk & 7) >> 1;
  const int qt = ((blk >> 3) << 1) | (blk & 1);
  const int q0 = qt << 6;
  const long bL = (long)b * LL;

  // Q fragments (all 64 rows, 4 chains): 64 VGPRs, from swizzled xbf
  uint2 qf[4][8];
  float qa[4];
  #pragma unroll
  for (int t = 0; t < 4; ++t) {
    const int row = q0 + 16 * t + l15;
    const u8* qrow = xbf + ((bL + row) << 8);
    const int key = row & 31;
    #pragma unroll
    for (int s = 0; s < 8; ++s)
      qf[t][s] = *(const uint2*)(qrow + (((q4 + 4 * s) ^ key) << 3));
    qa[t] = -0.5f * sqv[bL + row];
  }

  f32x16 oacc[2];
  #pragma unroll
  for (int rb = 0; rb < 2; ++rb)
    #pragma unroll
    for (int k = 0; k < 16; ++k) oacc[rb][k] = 0.f;
  float rsacc[4] = {0.f, 0.f, 0.f, 0.f};

  const u8* kbat = xbf + (bL << 8);
  // V segment base for this wave's O columns (d = 32w + l31), swizzled chunks (key = d&15)
  const u8* vseg = xT + (((long)(b << 8) + 32 * w + l31) << 12);
  const int vkey = l31 & 15;

  uint2 vfA[8], vfB[8];

  // prologue: DMA K tile 0 -> Kt[0]
  #pragma unroll
  for (int c = 0; c < 4; ++c) {
    int off = c * 8192 + tid * 16;
    dma16(kbat + off, Kt[0] + off);
  }
  __syncthreads();

#define TPE_ITER(IT, KCUR, KNXT, PPREV, PCUR, VFC, VFN)                                     \
  {                                                                                         \
    const int j0 = (IT) << 7;                                                               \
    if ((IT) < 31) { /* DMA K(it+1): full iteration of flight before the barrier drain */   \
      const u8* ks = kbat + ((long)((IT) + 1) << 15);                                       \
      _Pragma("unroll")                                                                     \
      for (int c = 0; c < 4; ++c) {                                                         \
        int off = c * 8192 + tid * 16;                                                      \
        dma16(ks + off, (KNXT) + off);                                                      \
      }                                                                                     \
    }                                                                                       \
    float4 skv4 = *(const float4*)(sqv + bL + j0 + 16 * w + 4 * q4);                        \
    if ((IT) != 0) { /* mm2 on previous tile: A = P(it-1) LDS, B = vf registers */          \
      _Pragma("unroll")                                                                     \
      for (int s = 0; s < 8; ++s) {                                                         \
        long a0 = *(const long*)((PPREV) + l31 * PSTR + 16 * s + 8 * q2);                   \
        long a1 = *(const long*)((PPREV) + (32 + l31) * PSTR + 16 * s + 8 * q2);            \
        long bv = LCAST(VFC[s]);                                                            \
        oacc[0] = __builtin_amdgcn_mfma_f32_32x32x16_fp8_fp8(a0, bv, oacc[0], 0, 0, 0);     \
        oacc[1] = __builtin_amdgcn_mfma_f32_32x32x16_fp8_fp8(a1, bv, oacc[1], 0, 0, 0);     \
      }                                                                                     \
    }                                                                                       \
    _Pragma("unroll") /* vf for THIS tile (consumed next iter, post-barrier) */             \
    for (int s = 0; s < 8; ++s)                                                             \
      VFN[s] = *(const uint2*)(vseg + j0 + (((2 * s + q2) ^ vkey) << 3));                   \
    { /* mm1: S^T = K.Q^T, 32-MFMA dense run, 4 independent chains */                       \
      const int krow = 16 * w + l15;                                                        \
      const int kkey = krow & 31;                                                           \
      const u8* kb2 = (KCUR) + krow * 256;                                                  \
      f32x4 sacc[4];                                                                        \
      _Pragma("unroll")                                                                     \
      for (int t = 0; t < 4; ++t) {                                                         \
        sacc[t][0] = 0.f; sacc[t][1] = 0.f; sacc[t][2] = 0.f; sacc[t][3] = 0.f;             \
      }                                                                                     \
      _Pragma("unroll")                                                                     \
      for (int s = 0; s < 8; ++s) {                                                         \
        uint2 kf = *(const uint2*)(kb2 + (((q4 + 4 * s) ^ kkey) << 3));                     \
        long av = LCAST(kf);                                                                \
        _Pragma("unroll")                                                                   \
        for (int t = 0; t < 4; ++t)                                                         \
          sacc[t] = __builtin_amdgcn_mfma_f32_16x16x32_fp8_fp8(av, LCAST(qf[t][s]), sacc[t], 0, 0, 0); \
      }                                                                                     \
      _Pragma("unroll") /* P = exp(min(0, g - 0.5||q||^2 - 0.5||k||^2)) -> LDS fp8 */       \
      for (int t = 0; t < 4; ++t) { /* lane: P[i=16t+l15][j=16w+4q4+0..3] */                \
        float p0 = __expf(fminf(fmaf(sacc[t][0], GSCALE, qa[t] + skv4.x), 0.f));            \
        float p1 = __expf(fminf(fmaf(sacc[t][1], GSCALE, qa[t] + skv4.y), 0.f));            \
        float p2 = __expf(fminf(fmaf(sacc[t][2], GSCALE, qa[t] + skv4.z), 0.f));            \
        float p3 = __expf(fminf(fmaf(sacc[t][3], GSCALE, qa[t] + skv4.w), 0.f));            \
        rsacc[t] += (p0 + p1) + (p2 + p3);                                                  \
        int pk = __builtin_amdgcn_cvt_pk_fp8_f32(p0, p1, 0, false);                         \
        pk = __builtin_amdgcn_cvt_pk_fp8_f32(p2, p3, pk, true);                             \
        *(int*)((PCUR) + (16 * t + l15) * PSTR + 16 * w + 4 * q4) = pk;                     \
      }                                                                                     \
    }                                                                                       \
    __syncthreads(); /* the ONLY barrier: P(it) visible, K(it+1) + vf(it) drained */        \
  }

  for (int it2 = 0; it2 < 16; ++it2) {
    TPE_ITER(2 * it2,     Kt[0], Kt[1], Ps[1], Ps[0], vfA, vfB)
    TPE_ITER(2 * it2 + 1, Kt[1], Kt[0], Ps[0], Ps[1], vfB, vfA)
  }
#undef TPE_ITER

  // ---- final mm2 (tile 31: P = Ps[1], V = vfA) ----
  #pragma unroll
  for (int s = 0; s < 8; ++s) {
    long a0 = *(const long*)(Ps[1] + l31 * PSTR + 16 * s + 8 * q2);
    long a1 = *(const long*)(Ps[1] + (32 + l31) * PSTR + 16 * s + 8 * q2);
    long bv = LCAST(vfA[s]);
    oacc[0] = __builtin_amdgcn_mfma_f32_32x32x16_fp8_fp8(a0, bv, oacc[0], 0, 0, 0);
    oacc[1] = __builtin_amdgcn_mfma_f32_32x32x16_fp8_fp8(a1, bv, oacc[1], 0, 0, 0);
  }

  // ---- epilogue: rowsum reduce; out = O/(16*l) + x + pe(inline) ----
  #pragma unroll
  for (int t = 0; t < 4; ++t) {
    float r = rsacc[t];
    r += __shfl_xor(r, 16);
    r += __shfl_xor(r, 32);
    if (lane < 16) lred[w][16 * t + l15] = r;
  }
  __syncthreads();
  if (tid < 64) {
    float s = 0.f;
    #pragma unroll
    for (int ww = 0; ww < 8; ++ww) s += lred[ww][tid];
    linv[tid] = 0.0625f / s;   // 1/16 undoes V pre-scale
  }
  __syncthreads();
  const int col = 32 * w + l31;
  const float freq = __expf((float)(col & ~1) * FREQC);
  #pragma unroll
  for (int rb = 0; rb < 2; ++rb) {
    #pragma unroll
    for (int reg = 0; reg < 16; ++reg) {
      int row = 32 * rb + 4 * q2 + (reg & 3) + 8 * (reg >> 2);
      int l = q0 + row;
      float ang = (float)l * freq;
      float pv = (col & 1) ? __cosf(ang) : __sinf(ang);
      long off = ((bL + l) << 8) + col;
      out[off] = oacc[rb][reg] * linv[row] + x[off] + pv;
    }
  }
}

extern "C" void kernel_launch(void* const* d_in, const int* in_sizes, int n_in,
                              void* d_out, int out_size, void* d_ws, size_t ws_size,
                              hipStream_t stream) {
  const float* x = (const float*)d_in[0];
  float* out = (float*)d_out;
  char* ws = (char*)d_ws;
  u8* xbf = (u8*)ws;                       // 4,194,304 B  (fp8 x, swizzled rows)
  u8* xT = (u8*)(ws + 4194304);            // 4,194,304 B  (fp8 x^T, swizzled segments)
  float* sq = (float*)(ws + 8388608);      //    65,536 B
  prep1<<<1024, 256, 0, stream>>>(x, xbf, xT, sq);
  tpe_main<<<256, 512, 0, stream>>>(xbf, xT, sq, x, out);
}